// Round 1
// baseline (279.960 us; speedup 1.0000x reference)
//
#include <hip/hip_runtime.h>
#include <math.h>

// Problem: B=16 rows, D=2^21 fp32 per row.
// loss = mean_i( sqrt( sum_j (out[i,j]-lab[i,j])^2 ) )
//
// R2 theory: partial kernel was latency-bound (VGPR=32 -> compiler serialized
// into load-pair -> waitcnt -> FMA, ~2 loads in flight/wave; 2.73 TB/s eff).
// This version batches 8 independent loads into register arrays before any
// FMA (4x MLP), uses 4 accumulators to break the serial chain, and launches
// an exact-fill persistent grid (2048 blocks = 8 blocks/CU, 32 waves/CU).

constexpr int B = 16;
constexpr int D = 2097152;                         // 2^21 floats per row
constexpr int THREADS = 256;                       // 4 waves per block
constexpr int BLOCKS_PER_ROW = 128;
constexpr int GRID = B * BLOCKS_PER_ROW;           // 2048 = 256 CUs * 8 blocks
constexpr int F4_PER_ROW = D / 4;                  // 524288
constexpr int F4_PER_BLOCK = F4_PER_ROW / BLOCKS_PER_ROW;   // 4096
constexpr int BATCH = 4;                           // float4 per stream per batch
constexpr int F4_PER_BATCH = THREADS * BATCH;      // 1024
constexpr int NBATCH = F4_PER_BLOCK / F4_PER_BATCH;         // 4

__global__ __launch_bounds__(THREADS, 8)           // 8 blocks/CU -> VGPR cap 64
void sqdiff_partial_kernel(const float4* __restrict__ out,
                           const float4* __restrict__ lab,
                           float* __restrict__ partials) {
    const int row   = blockIdx.x >> 7;             // / BLOCKS_PER_ROW
    const int chunk = blockIdx.x & (BLOCKS_PER_ROW - 1);
    const size_t blockbase = (size_t)row * F4_PER_ROW
                           + (size_t)chunk * F4_PER_BLOCK;

    float a0 = 0.0f, a1 = 0.0f, a2 = 0.0f, a3 = 0.0f;

#pragma unroll 1                                   // keep VGPRs <= 64: one batch live
    for (int b = 0; b < NBATCH; ++b) {
        const size_t idx = blockbase + (size_t)b * F4_PER_BATCH + threadIdx.x;

        // Issue all 8 loads back-to-back BEFORE any consumer -> 8 in flight.
        float4 o[BATCH], l[BATCH];
#pragma unroll
        for (int i = 0; i < BATCH; ++i) o[i] = out[idx + (size_t)i * THREADS];
#pragma unroll
        for (int i = 0; i < BATCH; ++i) l[i] = lab[idx + (size_t)i * THREADS];

#pragma unroll
        for (int i = 0; i < BATCH; ++i) {
            const float dx = o[i].x - l[i].x;
            const float dy = o[i].y - l[i].y;
            const float dz = o[i].z - l[i].z;
            const float dw = o[i].w - l[i].w;
            a0 = fmaf(dx, dx, a0);                 // 4 independent chains
            a1 = fmaf(dy, dy, a1);
            a2 = fmaf(dz, dz, a2);
            a3 = fmaf(dw, dw, a3);
        }
    }

    float acc = (a0 + a1) + (a2 + a3);

    // wave-64 tree reduce
#pragma unroll
    for (int off = 32; off > 0; off >>= 1)
        acc += __shfl_down(acc, off, 64);

    __shared__ float smem[THREADS / 64];
    const int lane = threadIdx.x & 63;
    const int wave = threadIdx.x >> 6;
    if (lane == 0) smem[wave] = acc;
    __syncthreads();

    if (threadIdx.x == 0) {
        // plain store, no atomic: partials laid out [row][chunk] == blockIdx.x
        partials[blockIdx.x] = smem[0] + smem[1] + smem[2] + smem[3];
    }
}

// One block, 1024 threads = 16 waves. Wave w reduces row w's 128 partials.
__global__ __launch_bounds__(1024)
void finalize_kernel(const float* __restrict__ partials,
                     float* __restrict__ loss) {
    const int wave = threadIdx.x >> 6;   // 0..15 == row
    const int lane = threadIdx.x & 63;

    float s = partials[wave * BLOCKS_PER_ROW + lane]
            + partials[wave * BLOCKS_PER_ROW + 64 + lane];

#pragma unroll
    for (int off = 32; off > 0; off >>= 1)
        s += __shfl_down(s, off, 64);

    __shared__ float row_dist[B];
    if (lane == 0) row_dist[wave] = sqrtf(s);
    __syncthreads();

    if (wave == 0) {
        float v = (lane < B) ? row_dist[lane] : 0.0f;
#pragma unroll
        for (int off = 32; off > 0; off >>= 1)
            v += __shfl_down(v, off, 64);
        if (lane == 0) loss[0] = v * (1.0f / (float)B);
    }
}

extern "C" void kernel_launch(void* const* d_in, const int* in_sizes, int n_in,
                              void* d_out, int out_size, void* d_ws, size_t ws_size,
                              hipStream_t stream) {
    const float4* out_p = (const float4*)d_in[0];
    const float4* lab_p = (const float4*)d_in[1];
    float* partials = (float*)d_ws;      // 2048 floats of scratch, fully overwritten

    sqdiff_partial_kernel<<<GRID, THREADS, 0, stream>>>(out_p, lab_p, partials);
    finalize_kernel<<<1, 1024, 0, stream>>>(partials, (float*)d_out);
}

// Round 2
// 271.655 us; speedup vs baseline: 1.0306x; 1.0306x over previous
//
#include <hip/hip_runtime.h>
#include <math.h>

// Problem: B=16 rows, D=2^21 fp32 per row.
// loss = mean_i( sqrt( sum_j (out[i,j]-lab[i,j])^2 ) )
//
// R3: R2's register-array batching was defeated by the compiler (VGPR fell to
// 24 -> loads re-sunk to load-pair/waitcnt/FMA, MLP~1-2, latency-bound at
// 2.7 TB/s eff). Key new evidence: an L3-resident dispatch (ord 97, ~0 HBM
// fetch) ran the SAME 99.5us -> not HBM-service-bound; waves sit with zero
// loads in flight. This version FORCES load clustering: register
// double-buffer (batch b+1 issued before computing batch b), pinned with
// __builtin_amdgcn_sched_barrier(0) so the scheduler cannot sink the loads.
// Fully unrolled -> all indices compile-time (no scratch). MLP ~4/wave at
// 8 waves/EU.

constexpr int B = 16;
constexpr int D = 2097152;                         // 2^21 floats per row
constexpr int THREADS = 256;                       // 4 waves per block
constexpr int BLOCKS_PER_ROW = 128;
constexpr int GRID = B * BLOCKS_PER_ROW;           // 2048 = 256 CUs * 8 blocks
constexpr int F4_PER_ROW = D / 4;                  // 524288
constexpr int F4_PER_BLOCK = F4_PER_ROW / BLOCKS_PER_ROW;   // 4096
constexpr int PAIRS = 2;                           // float4 pairs per batch
constexpr int F4_PER_BATCH = THREADS * PAIRS;      // 512
constexpr int NB = F4_PER_BLOCK / F4_PER_BATCH;    // 8 batches per thread

__global__ __launch_bounds__(THREADS, 8)           // 8 waves/EU -> VGPR cap 64
void sqdiff_partial_kernel(const float4* __restrict__ out,
                           const float4* __restrict__ lab,
                           float* __restrict__ partials) {
    const int row   = blockIdx.x >> 7;             // / BLOCKS_PER_ROW
    const int chunk = blockIdx.x & (BLOCKS_PER_ROW - 1);
    const size_t base = (size_t)row * F4_PER_ROW
                      + (size_t)chunk * F4_PER_BLOCK
                      + (size_t)threadIdx.x;

    // Register double-buffer: compute batch b while batch b+1's 4 loads are
    // in flight. Indices are all compile-time after full unroll.
    float4 ob[2][PAIRS], lb[2][PAIRS];

    // Prologue: batch 0 -> buffer 0.
#pragma unroll
    for (int k = 0; k < PAIRS; ++k) {
        ob[0][k] = out[base + (size_t)k * THREADS];
        lb[0][k] = lab[base + (size_t)k * THREADS];
    }

    float a0 = 0.0f, a1 = 0.0f, a2 = 0.0f, a3 = 0.0f;

#pragma unroll
    for (int b = 0; b < NB; ++b) {
        const int cur = b & 1;
        const int nxt = cur ^ 1;

        // Issue next batch's 4 loads BEFORE computing the current batch.
        if (b + 1 < NB) {
            const size_t noff = base + (size_t)(b + 1) * F4_PER_BATCH;
#pragma unroll
            for (int k = 0; k < PAIRS; ++k) {
                ob[nxt][k] = out[noff + (size_t)k * THREADS];
                lb[nxt][k] = lab[noff + (size_t)k * THREADS];
            }
        }

        // Compile-time scheduling fence: loads above may not sink below,
        // FMAs below may not hoist above. waitcnt inserter will then emit
        // vmcnt(4) here (current batch ready, next batch in flight).
        __builtin_amdgcn_sched_barrier(0);

#pragma unroll
        for (int k = 0; k < PAIRS; ++k) {
            const float dx = ob[cur][k].x - lb[cur][k].x;
            const float dy = ob[cur][k].y - lb[cur][k].y;
            const float dz = ob[cur][k].z - lb[cur][k].z;
            const float dw = ob[cur][k].w - lb[cur][k].w;
            a0 = fmaf(dx, dx, a0);                 // 4 independent chains
            a1 = fmaf(dy, dy, a1);
            a2 = fmaf(dz, dz, a2);
            a3 = fmaf(dw, dw, a3);
        }
    }

    float acc = (a0 + a1) + (a2 + a3);

    // wave-64 tree reduce
#pragma unroll
    for (int off = 32; off > 0; off >>= 1)
        acc += __shfl_down(acc, off, 64);

    __shared__ float smem[THREADS / 64];
    const int lane = threadIdx.x & 63;
    const int wave = threadIdx.x >> 6;
    if (lane == 0) smem[wave] = acc;
    __syncthreads();

    if (threadIdx.x == 0) {
        // plain store, no atomic: partials laid out [row][chunk] == blockIdx.x
        partials[blockIdx.x] = smem[0] + smem[1] + smem[2] + smem[3];
    }
}

// One block, 1024 threads = 16 waves. Wave w reduces row w's 128 partials.
__global__ __launch_bounds__(1024)
void finalize_kernel(const float* __restrict__ partials,
                     float* __restrict__ loss) {
    const int wave = threadIdx.x >> 6;   // 0..15 == row
    const int lane = threadIdx.x & 63;

    float s = partials[wave * BLOCKS_PER_ROW + lane]
            + partials[wave * BLOCKS_PER_ROW + 64 + lane];

#pragma unroll
    for (int off = 32; off > 0; off >>= 1)
        s += __shfl_down(s, off, 64);

    __shared__ float row_dist[B];
    if (lane == 0) row_dist[wave] = sqrtf(s);
    __syncthreads();

    if (wave == 0) {
        float v = (lane < B) ? row_dist[lane] : 0.0f;
#pragma unroll
        for (int off = 32; off > 0; off >>= 1)
            v += __shfl_down(v, off, 64);
        if (lane == 0) loss[0] = v * (1.0f / (float)B);
    }
}

extern "C" void kernel_launch(void* const* d_in, const int* in_sizes, int n_in,
                              void* d_out, int out_size, void* d_ws, size_t ws_size,
                              hipStream_t stream) {
    const float4* out_p = (const float4*)d_in[0];
    const float4* lab_p = (const float4*)d_in[1];
    float* partials = (float*)d_ws;      // 2048 floats of scratch, fully overwritten

    sqdiff_partial_kernel<<<GRID, THREADS, 0, stream>>>(out_p, lab_p, partials);
    finalize_kernel<<<1, 1024, 0, stream>>>(partials, (float*)d_out);
}